// Round 1
// baseline (959.047 us; speedup 1.0000x reference)
//
#include <hip/hip_runtime.h>

#define NB   8
#define NTOK 1024
#define DDIM 1024
#define NEXP 16
#define HDIM 4096
#define CAP  80

// -------- GEMM1 + exact GELU: Hid[b][m][h] = gelu(sum_k X[b][m][k] * W1[e][k][h])
// block 256 threads; tile M=80 (all rows), N=128, BK=16; thread tile 5x8
__global__ __launch_bounds__(256) void moe_gemm1(
    const float* __restrict__ X, const int* __restrict__ Y,
    const float* __restrict__ W1, float* __restrict__ Hid)
{
    const int b  = blockIdx.y;
    const int n0 = blockIdx.x * 128;
    const int e  = Y[b] & (NEXP - 1);
    const int tid = threadIdx.x;
    const int tx = tid & 15, ty = tid >> 4;

    __shared__ float As[16][CAP];    // [k][m]
    __shared__ float Bs[16][128];    // [k][n]

    float acc[5][8];
    #pragma unroll
    for (int r = 0; r < 5; ++r)
        #pragma unroll
        for (int j = 0; j < 8; ++j) acc[r][j] = 0.f;

    const float* Xb  = X  + (size_t)b * NTOK * DDIM;
    const float* W1e = W1 + (size_t)e * DDIM * HDIM;

    for (int k0 = 0; k0 < DDIM; k0 += 16) {
        for (int i = tid; i < CAP * 16; i += 256) {
            int m = i >> 4, k = i & 15;
            As[k][m] = Xb[(size_t)m * DDIM + k0 + k];
        }
        for (int i = tid; i < 16 * 128; i += 256) {
            int k = i >> 7, n = i & 127;
            Bs[k][n] = W1e[(size_t)(k0 + k) * HDIM + n0 + n];
        }
        __syncthreads();
        #pragma unroll
        for (int kk = 0; kk < 16; ++kk) {
            float a[5], bb[8];
            #pragma unroll
            for (int r = 0; r < 5; ++r) a[r] = As[kk][ty + 16 * r];
            #pragma unroll
            for (int j = 0; j < 8; ++j) bb[j] = Bs[kk][tx * 8 + j];
            #pragma unroll
            for (int r = 0; r < 5; ++r)
                #pragma unroll
                for (int j = 0; j < 8; ++j)
                    acc[r][j] += a[r] * bb[j];
        }
        __syncthreads();
    }

    float* Hb = Hid + (size_t)b * CAP * HDIM;
    #pragma unroll
    for (int r = 0; r < 5; ++r) {
        int m = ty + 16 * r;
        #pragma unroll
        for (int j = 0; j < 8; ++j) {
            int n = n0 + tx * 8 + j;
            float x = acc[r][j];
            float g = 0.5f * x * (1.0f + erff(x * 0.70710678118654752f));
            Hb[(size_t)m * HDIM + n] = g;
        }
    }
}

// -------- GEMM2: Out[b][m][d] += sum_k Hid[b][m][k] * W2[e][k][d]
// K split 4 ways over blockIdx.z, fp32 atomicAdd into zeroed output.
// block 256 threads; tile M=80, N=64, BK=16; thread tile 5x4
__global__ __launch_bounds__(256) void moe_gemm2(
    const float* __restrict__ Hid, const int* __restrict__ Y,
    const float* __restrict__ W2, float* __restrict__ Out)
{
    const int b  = blockIdx.y;
    const int n0 = blockIdx.x * 64;
    const int e  = Y[b] & (NEXP - 1);
    const int tid = threadIdx.x;
    const int tx = tid & 15, ty = tid >> 4;

    __shared__ float As[16][CAP];   // [k][m]
    __shared__ float Bs[16][64];    // [k][n]

    float acc[5][4];
    #pragma unroll
    for (int r = 0; r < 5; ++r)
        #pragma unroll
        for (int j = 0; j < 4; ++j) acc[r][j] = 0.f;

    const float* Hb  = Hid + (size_t)b * CAP * HDIM;
    const float* W2e = W2  + (size_t)e * HDIM * DDIM;
    const int kbeg = blockIdx.z * (HDIM / 4);
    const int kend = kbeg + (HDIM / 4);

    for (int k0 = kbeg; k0 < kend; k0 += 16) {
        for (int i = tid; i < CAP * 16; i += 256) {
            int m = i >> 4, k = i & 15;
            As[k][m] = Hb[(size_t)m * HDIM + k0 + k];
        }
        for (int i = tid; i < 16 * 64; i += 256) {
            int k = i >> 6, n = i & 63;
            Bs[k][n] = W2e[(size_t)(k0 + k) * DDIM + n0 + n];
        }
        __syncthreads();
        #pragma unroll
        for (int kk = 0; kk < 16; ++kk) {
            float a[5], bb[4];
            #pragma unroll
            for (int r = 0; r < 5; ++r) a[r] = As[kk][ty + 16 * r];
            #pragma unroll
            for (int j = 0; j < 4; ++j) bb[j] = Bs[kk][tx * 4 + j];
            #pragma unroll
            for (int r = 0; r < 5; ++r)
                #pragma unroll
                for (int j = 0; j < 4; ++j)
                    acc[r][j] += a[r] * bb[j];
        }
        __syncthreads();
    }

    float* Ob = Out + (size_t)b * NTOK * DDIM;
    #pragma unroll
    for (int r = 0; r < 5; ++r) {
        int m = ty + 16 * r;
        #pragma unroll
        for (int j = 0; j < 4; ++j) {
            int n = n0 + tx * 4 + j;
            atomicAdd(&Ob[(size_t)m * DDIM + n], acc[r][j]);
        }
    }
}

extern "C" void kernel_launch(void* const* d_in, const int* in_sizes, int n_in,
                              void* d_out, int out_size, void* d_ws, size_t ws_size,
                              hipStream_t stream) {
    const float* X  = (const float*)d_in[0];
    const int*   Y  = (const int*)d_in[1];
    const float* W1 = (const float*)d_in[2];
    const float* W2 = (const float*)d_in[3];
    float* Out = (float*)d_out;
    float* Hid = (float*)d_ws;   // 8*80*4096*4 = 10.5 MB

    // rows n >= CAP must be exactly zero; also provides the atomicAdd base.
    hipMemsetAsync(d_out, 0, (size_t)out_size * sizeof(float), stream);

    moe_gemm1<<<dim3(HDIM / 128, NB), 256, 0, stream>>>(X, Y, W1, Hid);
    moe_gemm2<<<dim3(DDIM / 64, NB, 4), 256, 0, stream>>>(Hid, Y, W2, Out);
}

// Round 2
// 472.292 us; speedup vs baseline: 2.0306x; 2.0306x over previous
//
#include <hip/hip_runtime.h>
#include <hip/hip_bf16.h>

#define NB   8
#define NTOK 1024
#define DDIM 1024
#define NEXP 16
#define HDIM 4096
#define CAP  80
#define BK   64

using bf16x8 = __attribute__((ext_vector_type(8))) __bf16;
using bf16x4 = __attribute__((ext_vector_type(4))) __bf16;
using f32x4  = __attribute__((ext_vector_type(4))) float;

// ---------------- GEMM1 + exact GELU ----------------
// Hid[b][m][h] = gelu(sum_k X[b][m][k] * W1[e][k][h]),  m<80, bf16 out.
// Block: 256 thr = 4 waves, BN=64 (1 n-tile of 16 per wave), all M=80 (5 m-tiles).
// A (X): LDS-staged bf16 [80][BK+8]; B (W1): direct global->reg frags (no LDS).
__global__ __launch_bounds__(256) void moe_g1(
    const float* __restrict__ X, const int* __restrict__ Y,
    const float* __restrict__ W1, __bf16* __restrict__ Hid)
{
    const int b     = blockIdx.y;
    const int e     = Y[b] & (NEXP - 1);
    const int nbase = blockIdx.x * 64;
    const int tid   = threadIdx.x;
    const int w     = tid >> 6;       // wave 0..3
    const int l     = tid & 63;
    const int q     = l >> 4;         // quad 0..3
    const int r     = l & 15;
    const int n     = nbase + w * 16 + r;

    __shared__ __bf16 As[CAP][BK + 8];   // pad 8 bf16 = 16B -> conflict-free b64 wr / b128 rd

    const float* Xb  = X  + (size_t)b * NTOK * DDIM;
    const float* W1e = W1 + (size_t)e * DDIM * HDIM;

    f32x4 acc[5];
    #pragma unroll
    for (int i = 0; i < 5; ++i) acc[i] = f32x4{0.f, 0.f, 0.f, 0.f};

    for (int k0 = 0; k0 < DDIM; k0 += BK) {
        // ---- B fragment loads first (global fp32, coalesced across lanes in n)
        float bv[16];
        const float* bp = W1e + (size_t)(k0 + q * 8) * HDIM + n;
        #pragma unroll
        for (int s = 0; s < 2; ++s)
            #pragma unroll
            for (int j = 0; j < 8; ++j)
                bv[s * 8 + j] = bp[(size_t)(s * 32 + j) * HDIM];

        // ---- stage A chunk (fp32 -> bf16)
        __syncthreads();
        #pragma unroll
        for (int it = 0; it < 5; ++it) {
            int i   = tid + 256 * it;        // 0..1279
            int row = i >> 4, kg = i & 15;
            float4 v = *(const float4*)&Xb[(size_t)row * DDIM + k0 + kg * 4];
            bf16x4 p = {(__bf16)v.x, (__bf16)v.y, (__bf16)v.z, (__bf16)v.w};
            *(bf16x4*)&As[row][kg * 4] = p;
        }
        __syncthreads();

        // ---- MFMA: 2 k-steps of 32, 5 m-tiles
        #pragma unroll
        for (int s = 0; s < 2; ++s) {
            bf16x8 bf;
            #pragma unroll
            for (int j = 0; j < 8; ++j) bf[j] = (__bf16)bv[s * 8 + j];
            #pragma unroll
            for (int mt = 0; mt < 5; ++mt) {
                bf16x8 af = *(const bf16x8*)&As[mt * 16 + r][s * 32 + q * 8];
                acc[mt] = __builtin_amdgcn_mfma_f32_16x16x32_bf16(af, bf, acc[mt], 0, 0, 0);
            }
        }
    }

    // ---- epilogue: exact GELU, bf16 store. C/D layout: col=l&15, row=q*4+reg.
    __bf16* Hb = Hid + (size_t)b * CAP * HDIM;
    #pragma unroll
    for (int mt = 0; mt < 5; ++mt)
        #pragma unroll
        for (int v = 0; v < 4; ++v) {
            int m = mt * 16 + q * 4 + v;
            float x = acc[mt][v];
            float g = 0.5f * x * (1.0f + erff(x * 0.70710678118654752f));
            Hb[(size_t)m * HDIM + n] = (__bf16)g;
        }
}

// ---------------- GEMM2 ----------------
// Out[b][m][d] += sum_h Hid[b][m][h] * W2[e][h][d]; K=4096 split 4 (blockIdx.z),
// fp32 atomicAdd into zeroed Out.
__global__ __launch_bounds__(256) void moe_g2(
    const __bf16* __restrict__ Hid, const int* __restrict__ Y,
    const float* __restrict__ W2, float* __restrict__ Out)
{
    const int b     = blockIdx.y;
    const int e     = Y[b] & (NEXP - 1);
    const int nbase = blockIdx.x * 64;
    const int kz    = blockIdx.z * (HDIM / 4);
    const int tid   = threadIdx.x;
    const int w     = tid >> 6;
    const int l     = tid & 63;
    const int q     = l >> 4;
    const int r     = l & 15;
    const int n     = nbase + w * 16 + r;

    __shared__ __bf16 As[CAP][BK + 8];

    const __bf16* Hb  = Hid + (size_t)b * CAP * HDIM;
    const float*  W2e = W2  + (size_t)e * HDIM * DDIM;

    f32x4 acc[5];
    #pragma unroll
    for (int i = 0; i < 5; ++i) acc[i] = f32x4{0.f, 0.f, 0.f, 0.f};

    for (int k0 = kz; k0 < kz + HDIM / 4; k0 += BK) {
        float bv[16];
        const float* bp = W2e + (size_t)(k0 + q * 8) * DDIM + n;
        #pragma unroll
        for (int s = 0; s < 2; ++s)
            #pragma unroll
            for (int j = 0; j < 8; ++j)
                bv[s * 8 + j] = bp[(size_t)(s * 32 + j) * DDIM];

        __syncthreads();
        #pragma unroll
        for (int it = 0; it < 5; ++it) {
            int i   = tid + 256 * it;
            int row = i >> 4, kg = i & 15;
            uint2 v = *(const uint2*)&Hb[(size_t)row * HDIM + k0 + kg * 4]; // 4 bf16
            *(uint2*)&As[row][kg * 4] = v;
        }
        __syncthreads();

        #pragma unroll
        for (int s = 0; s < 2; ++s) {
            bf16x8 bf;
            #pragma unroll
            for (int j = 0; j < 8; ++j) bf[j] = (__bf16)bv[s * 8 + j];
            #pragma unroll
            for (int mt = 0; mt < 5; ++mt) {
                bf16x8 af = *(const bf16x8*)&As[mt * 16 + r][s * 32 + q * 8];
                acc[mt] = __builtin_amdgcn_mfma_f32_16x16x32_bf16(af, bf, acc[mt], 0, 0, 0);
            }
        }
    }

    float* Ob = Out + (size_t)b * NTOK * DDIM;
    #pragma unroll
    for (int mt = 0; mt < 5; ++mt)
        #pragma unroll
        for (int v = 0; v < 4; ++v) {
            int m = mt * 16 + q * 4 + v;
            atomicAdd(&Ob[(size_t)m * DDIM + n], acc[mt][v]);
        }
}

extern "C" void kernel_launch(void* const* d_in, const int* in_sizes, int n_in,
                              void* d_out, int out_size, void* d_ws, size_t ws_size,
                              hipStream_t stream) {
    const float* X  = (const float*)d_in[0];
    const int*   Y  = (const int*)d_in[1];
    const float* W1 = (const float*)d_in[2];
    const float* W2 = (const float*)d_in[3];
    float*  Out = (float*)d_out;
    __bf16* Hid = (__bf16*)d_ws;   // 8*80*4096*2 = 5.24 MB

    // rows n >= CAP must be exactly zero; also the atomicAdd base for split-K.
    hipMemsetAsync(d_out, 0, (size_t)out_size * sizeof(float), stream);

    moe_g1<<<dim3(HDIM / 64, NB), 256, 0, stream>>>(X, Y, W1, Hid);
    moe_g2<<<dim3(DDIM / 64, NB, 4), 256, 0, stream>>>(Hid, Y, W2, Out);
}